// Round 10
// baseline (307.629 us; speedup 1.0000x reference)
//
#include <hip/hip_runtime.h>
#include <hip/hip_bf16.h>
#include <cstdint>
#include <cstddef>

// BaseNet: B=262144 samples, d=512.
// H = relu(reshape(combined,[2B,512]) @ W_in + b_in)   [2B,128]
// m[s] = 0.5*(H[2s]+H[2s+1])                           [B,128]
// g1 = relu(m @ W1 + b1); g2 = relu(g1 @ W2 + b2)      [B,128],[B,64]
// out = sigmoid(g2 . (W_out[:64]+W_out[64:]) + b_out)  [B]
//
// Round-10: PURE-STREAM loader test. All prior kA variants read A with the
// MFMA row-per-lane pattern (strided segments); all converged at 4.6-4.8 TB/s.
// This kernel reads A with the copy-ubench pattern (1KB lane-contiguous per
// wave instr, block walks 4MB sequentially), cvt->bf16 in reg, ds_write to a
// swizzled LDS tile. MFMA is N-sliced: W_in slice (16 cols) in 64 VGPRs/wave,
// so LDS = 2x32KB A dbuf + 2x4KB bounce = 72KB. T14 pipeline, 1 barrier/tile.

#define NROWS   524288   // 2B
#define NSAMP   262144   // B

typedef __attribute__((ext_vector_type(8))) short  bf16x8;
typedef __attribute__((ext_vector_type(4))) float  f32x4;
typedef __attribute__((ext_vector_type(2))) unsigned int u32x2;

#define LGKM0() asm volatile("s_waitcnt lgkmcnt(0)" ::: "memory")
#define VMW0()  asm volatile("s_waitcnt vmcnt(0)" ::: "memory")
#define BAR()   __builtin_amdgcn_s_barrier()

__device__ __forceinline__ unsigned short f2bf(float f) {
    unsigned u = __float_as_uint(f);
    u += 0x7fffu + ((u >> 16) & 1u);   // round-to-nearest-even
    return (unsigned short)(u >> 16);
}

__device__ __forceinline__ f32x4 mfma16(bf16x8 a, bf16x8 b, f32x4 c) {
    return __builtin_amdgcn_mfma_f32_16x16x32_bf16(a, b, c, 0, 0, 0);
}

// ---------------- workspace layout (bytes) ----------------
#define WS_M     0                       // Mf frag-layout [16384 F][4 ks][64 l][8] bf16 = 64 MB
#define WS_WIN   67108864                // Win frags: 16*8*64*8 bf16 = 131072 B
#define WS_W1    67239936                // W1 frags:  4*8*64*8 bf16 = 32768 B
#define WS_W2    67272704                // W2 frags:  4*4*64*8 bf16 = 16384 B
#define WS_WEFF  67289088                // 64 floats

// ---------------- prep: pack weights to MFMA B-fragment layout --------------
// ALL standard: frag (kt,n): lane l slot j holds W[kt*32+(l>>4)*8+j][n*16+(l&15)].
__global__ void prep_kernel(const float* __restrict__ W_in,
                            const float* __restrict__ W1,
                            const float* __restrict__ W2,
                            const float* __restrict__ W_out,
                            unsigned short* __restrict__ fWin,
                            unsigned short* __restrict__ fW1,
                            unsigned short* __restrict__ fW2,
                            float* __restrict__ weff) {
    int tid = blockIdx.x * 256 + threadIdx.x;
    if (tid < 65536) {                       // W_in [512][128]: KT=16, NT=8
        int e = tid;
        int j = e & 7, l = (e >> 3) & 63, rest = e >> 9;
        int n = rest & 7, kt = rest >> 3;
        int k = kt * 32 + ((l >> 4) << 3) + j;
        int col = n * 16 + (l & 15);
        fWin[e] = f2bf(W_in[k * 128 + col]);
    } else if (tid < 65536 + 16384) {        // W1 [128][128]: KT=4, NT=8
        int e = tid - 65536;
        int j = e & 7, l = (e >> 3) & 63, rest = e >> 9;
        int n = rest & 7, kt = rest >> 3;
        int k = kt * 32 + ((l >> 4) << 3) + j;
        int col = n * 16 + (l & 15);
        fW1[e] = f2bf(W1[k * 128 + col]);
    } else if (tid < 65536 + 16384 + 8192) { // W2 [128][64]: KT=4, NT=4
        int e = tid - 65536 - 16384;
        int j = e & 7, l = (e >> 3) & 63, rest = e >> 9;
        int n = rest & 3, kt = rest >> 2;
        int k = kt * 32 + ((l >> 4) << 3) + j;
        int col = n * 16 + (l & 15);
        fW2[e] = f2bf(W2[k * 64 + col]);
    } else if (tid < 65536 + 16384 + 8192 + 64) {
        int c = tid - (65536 + 16384 + 8192);
        weff[c] = W_out[c] + W_out[64 + c];
    }
}

// ---------------- kernel A: GEMM + bias/relu + node-mean -> Mf --------------
// 256 blocks x 512 thr = 8 waves (2/EU; waves_per_eu(2,2) pins 256 VGPR).
// Block owns 2048 CONTIGUOUS rows = 64 tiles of 32 rows (4MB sequential walk).
// Loader (all waves): 8x f32x4 pure-stream loads/thread/tile (1KB per wave
// instr), cvt_pk->bf16, ds_write_b64 into swizzled [32 r][1024B] tile
// (byte ^= (row&7)<<4; per-8-lane-phase conflict-free on both sides).
// Compute: N-sliced — wave w owns cols w*16..+16 with W_in frags in 64 VGPRs;
// per tile 2 rowtiles x 16 kg MFMA, acc = 2x f32x4 only.
// Per tile: issue L(t+1) -> compute(t)+epi -> vmcnt(0) -> cvt+write(t+1) ->
// barrier -> Mf store(t) from dbuf bounce. One barrier per tile.
__global__ void __launch_bounds__(512) __attribute__((amdgpu_waves_per_eu(2, 2)))
kA(const float* __restrict__ A,              // [2B][512] fp32 (= combined)
   const unsigned short* __restrict__ fWin,  // frag layout (standard)
   const float* __restrict__ b_in,
   unsigned short* __restrict__ Mf) {        // frag-layout m
    __shared__ __align__(16) char lds[73728];   // 72 KB
    char* buf0 = lds;                           // A tile ping (32 KB)
    char* buf1 = lds + 32768;                   // A tile pong
    char* bnc0 = lds + 65536;                   // bounce ping (4 KB)
    char* bnc1 = lds + 69632;                   // bounce pong

    const int tid = threadIdx.x, w = tid >> 6, l = tid & 63;
    const int lr = l & 15, lg = l >> 4;

    // W_in column-slice (cols w*16..w*16+15) in registers: 16 frags = 64 VGPR
    bf16x8 wfr[16];
    #pragma unroll
    for (int kt = 0; kt < 16; ++kt)
        wfr[kt] = *(const bf16x8*)&fWin[((kt * 8 + w) * 64 + l) * 8];
    const float bb = b_in[w * 16 + lr];

    const float* Ablk = A + (size_t)blockIdx.x * 2048 * 512;
    const int lrow  = tid >> 7;                 // + r*4 = row within tile
    const int lcol2 = ((tid * 4) & 511) * 2;    // byte col within row

    f32x4 stg[8];
    f32x4 acc0, acc1;

    #define ISSUE(t) { const float* p = Ablk + (size_t)(t) * 16384 + tid * 4; \
        _Pragma("unroll") for (int r = 0; r < 8; ++r) stg[r] = *(const f32x4*)(p + r * 2048); }
    #define CVTWR(buf) { _Pragma("unroll") \
        for (int r = 0; r < 8; ++r) { \
            const int row = r * 4 + lrow; \
            char* d = (buf) + row * 1024 + (lcol2 ^ ((row & 7) << 4)); \
            unsigned pa, pb; \
            asm("v_cvt_pk_bf16_f32 %0, %1, %2" : "=v"(pa) : "v"(stg[r][0]), "v"(stg[r][1])); \
            asm("v_cvt_pk_bf16_f32 %0, %1, %2" : "=v"(pb) : "v"(stg[r][2]), "v"(stg[r][3])); \
            u32x2 pk; pk[0] = pa; pk[1] = pb; \
            *(u32x2*)d = pk; } }

    // prologue: tile 0 staged
    ISSUE(0); VMW0(); CVTWR(buf0); LGKM0(); BAR();

    for (int t = 0; t < 64; ++t) {
        char* cur = (t & 1) ? buf1 : buf0;
        char* nxt = (t & 1) ? buf0 : buf1;
        char* bc  = (t & 1) ? bnc1 : bnc0;
        if (t < 63) ISSUE(t + 1);      // pure-stream loads, in flight across compute

        // ---- compute: rows {lr, 16+lr}, cols w*16..+16, K=512 ----
        acc0 = (f32x4){0.f, 0.f, 0.f, 0.f};
        acc1 = (f32x4){0.f, 0.f, 0.f, 0.f};
        #pragma unroll
        for (int kg = 0; kg < 16; ++kg) {
            const int co = kg * 64 + lg * 16;
            const int sw0 = co ^ ((lr & 7) << 4);
            bf16x8 a0v = *(const bf16x8*)(cur + lr * 1024 + sw0);
            bf16x8 a1v = *(const bf16x8*)(cur + (16 + lr) * 1024 + sw0);
            acc0 = mfma16(a0v, wfr[kg], acc0);
            acc1 = mfma16(a1v, wfr[kg], acc1);
        }

        // ---- epilogue: bias+relu+pair-mean -> swizzled bounce [16 s][256B] --
        // C layout: row = lg*4+rr (within rowtile), col = w*16+lr.
        {
            const int c2 = (w * 16 + lr) * 2;
            float m0 = 0.5f * (fmaxf(acc0[0] + bb, 0.f) + fmaxf(acc0[1] + bb, 0.f));
            float m1 = 0.5f * (fmaxf(acc0[2] + bb, 0.f) + fmaxf(acc0[3] + bb, 0.f));
            int s0 = 2 * lg, s1 = s0 + 1;
            *(unsigned short*)(bc + s0 * 256 + (c2 ^ ((s0 & 7) << 4))) = f2bf(m0);
            *(unsigned short*)(bc + s1 * 256 + (c2 ^ ((s1 & 7) << 4))) = f2bf(m1);
            float m2 = 0.5f * (fmaxf(acc1[0] + bb, 0.f) + fmaxf(acc1[1] + bb, 0.f));
            float m3 = 0.5f * (fmaxf(acc1[2] + bb, 0.f) + fmaxf(acc1[3] + bb, 0.f));
            int s2 = 8 + 2 * lg, s3 = s2 + 1;
            *(unsigned short*)(bc + s2 * 256 + (c2 ^ ((s2 & 7) << 4))) = f2bf(m2);
            *(unsigned short*)(bc + s3 * 256 + (c2 ^ ((s3 & 7) << 4))) = f2bf(m3);
        }

        if (t < 63) { VMW0(); CVTWR(nxt); }   // loads covered by compute above
        LGKM0(); BAR();                        // tile t+1 ready; bounce visible

        // ---- Mf store (waves 0..3, ks = w): 1KB contiguous per wave ----
        if (w < 4) {
            int roff = lr * 256 + ((w * 64 + lg * 16) ^ ((lr & 7) << 4));
            bf16x8 v = *(const bf16x8*)(bc + roff);
            size_t F = (size_t)blockIdx.x * 64 + (size_t)t;
            *(bf16x8*)&Mf[F * 2048 + (size_t)w * 512 + (size_t)l * 8] = v;
        }
        // bounce[t&1] is re-written only at epi(t+2) > barrier(t+1) > this read.
    }
    #undef ISSUE
    #undef CVTWR
}

// ---------------- kernel B: m -> g1 -> g2 -> sigmoid(score) -----------------
// (R9 verbatim, passed) 512 blocks, A-frags load 1KB-contiguous from Mf.
__global__ void __launch_bounds__(256, 2)
kB(const unsigned short* __restrict__ Mf,
   const unsigned short* __restrict__ fW1,
   const unsigned short* __restrict__ fW2,
   const float* __restrict__ weff,
   const float* __restrict__ b1,
   const float* __restrict__ b2,
   const float* __restrict__ b_out,
   float* __restrict__ out) {
    __shared__ unsigned short lw1[16384];       // 32 KB
    __shared__ unsigned short lw2[8192];        // 16 KB
    __shared__ unsigned short bounce[4][2048];  // 4 waves x 4 KB
    {
        int tid = threadIdx.x;
        const f32x4* s1 = (const f32x4*)fW1;
        f32x4* d1 = (f32x4*)lw1;
        #pragma unroll
        for (int i = 0; i < 8; ++i) d1[i * 256 + tid] = s1[i * 256 + tid];
        const f32x4* s2 = (const f32x4*)fW2;
        f32x4* d2 = (f32x4*)lw2;
        #pragma unroll
        for (int i = 0; i < 4; ++i) d2[i * 256 + tid] = s2[i * 256 + tid];
    }
    __syncthreads();
    const int w = threadIdx.x >> 6, l = threadIdx.x & 63;
    const int lr = l & 15, lg = l >> 4;
    float b1v[8], b2v[4], wev[4];
    #pragma unroll
    for (int n = 0; n < 8; ++n) b1v[n] = b1[n * 16 + lr];
    #pragma unroll
    for (int n = 0; n < 4; ++n) { b2v[n] = b2[n * 16 + lr]; wev[n] = weff[n * 16 + lr]; }
    const float bo = b_out[0];

    for (int t = blockIdx.x; t < NSAMP / 64; t += 512) {
        const int s0 = t * 64 + w * 16;
        const size_t F = (size_t)t * 4 + (size_t)w;
        f32x4 acc1[8];
        #pragma unroll
        for (int n = 0; n < 8; ++n) acc1[n] = (f32x4){0.f, 0.f, 0.f, 0.f};
        #pragma unroll
        for (int ks = 0; ks < 4; ++ks) {
            bf16x8 af = *(const bf16x8*)&Mf[F * 2048 + ks * 512 + l * 8];
            #pragma unroll
            for (int n = 0; n < 8; ++n) {
                bf16x8 bf = *(const bf16x8*)&lw1[((ks * 8 + n) * 64 + l) * 8];
                acc1[n] = __builtin_amdgcn_mfma_f32_16x16x32_bf16(af, bf, acc1[n], 0, 0, 0);
            }
        }
        #pragma unroll
        for (int n = 0; n < 8; ++n) {
            #pragma unroll
            for (int rr = 0; rr < 4; ++rr) {
                float g = fmaxf(acc1[n][rr] + b1v[n], 0.f);
                int row = lg * 4 + rr, col = n * 16 + lr;
                int boff = row * 256 + ((col * 2) ^ ((row & 7) << 4));
                bounce[w][boff >> 1] = f2bf(g);
            }
        }
        f32x4 acc2[4];
        #pragma unroll
        for (int n = 0; n < 4; ++n) acc2[n] = (f32x4){0.f, 0.f, 0.f, 0.f};
        #pragma unroll
        for (int ks = 0; ks < 4; ++ks) {
            int roff = lr * 256 + ((ks * 64 + lg * 16) ^ ((lr & 7) << 4));
            bf16x8 af2 = *(const bf16x8*)((const char*)&bounce[w][0] + roff);
            #pragma unroll
            for (int n = 0; n < 4; ++n) {
                bf16x8 bf = *(const bf16x8*)&lw2[((ks * 4 + n) * 64 + l) * 8];
                acc2[n] = __builtin_amdgcn_mfma_f32_16x16x32_bf16(af2, bf, acc2[n], 0, 0, 0);
            }
        }
        float p0 = 0.f, p1 = 0.f, p2 = 0.f, p3 = 0.f;
        #pragma unroll
        for (int n = 0; n < 4; ++n) {
            p0 += fmaxf(acc2[n][0] + b2v[n], 0.f) * wev[n];
            p1 += fmaxf(acc2[n][1] + b2v[n], 0.f) * wev[n];
            p2 += fmaxf(acc2[n][2] + b2v[n], 0.f) * wev[n];
            p3 += fmaxf(acc2[n][3] + b2v[n], 0.f) * wev[n];
        }
        #pragma unroll
        for (int m = 1; m < 16; m <<= 1) {
            p0 += __shfl_xor(p0, m);
            p1 += __shfl_xor(p1, m);
            p2 += __shfl_xor(p2, m);
            p3 += __shfl_xor(p3, m);
        }
        float s0f = 1.f / (1.f + expf(-(p0 + bo)));
        float s1f = 1.f / (1.f + expf(-(p1 + bo)));
        float s2f = 1.f / (1.f + expf(-(p2 + bo)));
        float s3f = 1.f / (1.f + expf(-(p3 + bo)));
        if (lr < 4) {
            float v = (lr == 0) ? s0f : (lr == 1) ? s1f : (lr == 2) ? s2f : s3f;
            out[s0 + lg * 4 + lr] = v;
        }
    }
}

// ---------------- host launcher ----------------
extern "C" void kernel_launch(void* const* d_in, const int* in_sizes, int n_in,
                              void* d_out, int out_size, void* d_ws, size_t ws_size,
                              hipStream_t stream) {
    const float* combined = (const float*)d_in[0];
    const float* W_in  = (const float*)d_in[1];
    const float* b_in  = (const float*)d_in[2];
    const float* W1    = (const float*)d_in[3];
    const float* b1    = (const float*)d_in[4];
    const float* W2    = (const float*)d_in[5];
    const float* b2    = (const float*)d_in[6];
    const float* W_out = (const float*)d_in[7];
    const float* b_out = (const float*)d_in[8];
    float* out = (float*)d_out;

    char* ws = (char*)d_ws;
    unsigned short* Mf   = (unsigned short*)(ws + WS_M);
    unsigned short* fWin = (unsigned short*)(ws + WS_WIN);
    unsigned short* fW1  = (unsigned short*)(ws + WS_W1);
    unsigned short* fW2  = (unsigned short*)(ws + WS_W2);
    float* weff          = (float*)(ws + WS_WEFF);

    prep_kernel<<<(65536 + 16384 + 8192 + 64 + 255) / 256, 256, 0, stream>>>(
        W_in, W1, W2, W_out, fWin, fW1, fW2, weff);
    kA<<<256, 512, 0, stream>>>(combined, fWin, b_in, Mf);
    kB<<<512, 256, 0, stream>>>(Mf, fW1, fW2, weff, b1, b2, b_out, out);
}

// Round 11
// 291.001 us; speedup vs baseline: 1.0571x; 1.0571x over previous
//
#include <hip/hip_runtime.h>
#include <hip/hip_bf16.h>
#include <cstdint>
#include <cstddef>

// BaseNet: B=262144 samples, d=512.
// H = relu(reshape(combined,[2B,512]) @ W_in + b_in)   [2B,128]
// m[s] = 0.5*(H[2s]+H[2s+1])                           [B,128]
// g1 = relu(m @ W1 + b1); g2 = relu(g1 @ W2 + b2)      [B,128],[B,64]
// out = sigmoid(g2 . (W_out[:64]+W_out[64:]) + b_out)  [B]
//
// Round-11: global_load_lds A-staging (the one untested big lever).
// Five read structures all converged at ~4.6 TB/s with VGPR-returned loads;
// global_load_lds DMAs HBM->LDS without the VGPR return path (m93->m97 +69%).
// A staged fp32: linear LDS dest + inverse-swizzled per-lane SOURCE (rule #21),
// read side mirrors the XOR -> conflict-balanced. N-sliced MFMA (W_in slice in
// 64 VGPR/wave), cvt fp32->bf16 at the LDS->reg boundary. 1 barrier/tile.

#define NROWS   524288   // 2B
#define NSAMP   262144   // B

typedef __attribute__((ext_vector_type(8))) short  bf16x8;
typedef __attribute__((ext_vector_type(4))) float  f32x4;

#define LGKM0() asm volatile("s_waitcnt lgkmcnt(0)" ::: "memory")
#define VMW0()  asm volatile("s_waitcnt vmcnt(0)" ::: "memory")
#define BAR()   __builtin_amdgcn_s_barrier()

#define GLOAD_LDS(gsrc, ldst) \
    __builtin_amdgcn_global_load_lds( \
        (const __attribute__((address_space(1))) void*)(gsrc), \
        (__attribute__((address_space(3))) void*)(ldst), 16, 0, 0)

__device__ __forceinline__ unsigned short f2bf(float f) {
    unsigned u = __float_as_uint(f);
    u += 0x7fffu + ((u >> 16) & 1u);   // round-to-nearest-even
    return (unsigned short)(u >> 16);
}

// packed bf16 convert: 4x v_cvt_pk_bf16_f32 (RNE, same numerics as f2bf)
__device__ __forceinline__ bf16x8 cvt8(f32x4 lo, f32x4 hi) {
    union { unsigned u[4]; bf16x8 v; } r;
    asm("v_cvt_pk_bf16_f32 %0, %1, %2" : "=v"(r.u[0]) : "v"(lo[0]), "v"(lo[1]));
    asm("v_cvt_pk_bf16_f32 %0, %1, %2" : "=v"(r.u[1]) : "v"(lo[2]), "v"(lo[3]));
    asm("v_cvt_pk_bf16_f32 %0, %1, %2" : "=v"(r.u[2]) : "v"(hi[0]), "v"(hi[1]));
    asm("v_cvt_pk_bf16_f32 %0, %1, %2" : "=v"(r.u[3]) : "v"(hi[2]), "v"(hi[3]));
    return r.v;
}

__device__ __forceinline__ f32x4 mfma16(bf16x8 a, bf16x8 b, f32x4 c) {
    return __builtin_amdgcn_mfma_f32_16x16x32_bf16(a, b, c, 0, 0, 0);
}

// ---------------- workspace layout (bytes) ----------------
#define WS_M     0                       // Mf frag-layout [16384 F][4 ks][64 l][8] bf16 = 64 MB
#define WS_WIN   67108864                // Win frags: 16*8*64*8 bf16 = 131072 B
#define WS_W1    67239936                // W1 frags:  4*8*64*8 bf16 = 32768 B
#define WS_W2    67272704                // W2 frags:  4*4*64*8 bf16 = 16384 B
#define WS_WEFF  67289088                // 64 floats

// ---------------- prep: pack weights to MFMA B-fragment layout --------------
// ALL standard: frag (kt,n): lane l slot j holds W[kt*32+(l>>4)*8+j][n*16+(l&15)].
__global__ void prep_kernel(const float* __restrict__ W_in,
                            const float* __restrict__ W1,
                            const float* __restrict__ W2,
                            const float* __restrict__ W_out,
                            unsigned short* __restrict__ fWin,
                            unsigned short* __restrict__ fW1,
                            unsigned short* __restrict__ fW2,
                            float* __restrict__ weff) {
    int tid = blockIdx.x * 256 + threadIdx.x;
    if (tid < 65536) {                       // W_in [512][128]: KT=16, NT=8
        int e = tid;
        int j = e & 7, l = (e >> 3) & 63, rest = e >> 9;
        int n = rest & 7, kt = rest >> 3;
        int k = kt * 32 + ((l >> 4) << 3) + j;
        int col = n * 16 + (l & 15);
        fWin[e] = f2bf(W_in[k * 128 + col]);
    } else if (tid < 65536 + 16384) {        // W1 [128][128]: KT=4, NT=8
        int e = tid - 65536;
        int j = e & 7, l = (e >> 3) & 63, rest = e >> 9;
        int n = rest & 7, kt = rest >> 3;
        int k = kt * 32 + ((l >> 4) << 3) + j;
        int col = n * 16 + (l & 15);
        fW1[e] = f2bf(W1[k * 128 + col]);
    } else if (tid < 65536 + 16384 + 8192) { // W2 [128][64]: KT=4, NT=4
        int e = tid - 65536 - 16384;
        int j = e & 7, l = (e >> 3) & 63, rest = e >> 9;
        int n = rest & 3, kt = rest >> 2;
        int k = kt * 32 + ((l >> 4) << 3) + j;
        int col = n * 16 + (l & 15);
        fW2[e] = f2bf(W2[k * 64 + col]);
    } else if (tid < 65536 + 16384 + 8192 + 64) {
        int c = tid - (65536 + 16384 + 8192);
        weff[c] = W_out[c] + W_out[64 + c];
    }
}

// ---------------- kernel A: GEMM + bias/relu + node-mean -> Mf --------------
// 256 blocks x 512 thr = 8 waves (2/EU; waves_per_eu(2,2) pins 256 VGPR).
// Block owns 2048 contiguous rows = 64 tiles of 32 rows.
// Staging: global_load_lds width-16, fp32, 8 instrs/wave/tile (wave w owns
// rows w*4..w*4+3). LDS dest LINEAR; per-lane global SOURCE carries the
// inverse XOR swizzle (16B units: u_global = u_lds ^ (row&7)) so the read
// side at addr row*2048 + ((s^(row&7))*16) is conflict-balanced (2-way max).
// Compute: N-sliced, wave w owns cols w*16..+16, W_in frags in 64 VGPR;
// per tile 2 rowtiles x 16 kg: 2x ds_read_b128(fp32) -> cvt_pk -> MFMA.
// Per tile: ISSUE(t+1) -> compute(t) -> epilogue -> lgkm0+vmcnt0 -> barrier
// -> Mf store. LDS: 2x64KB A dbuf + 2x4KB bounce = 136 KB.
__global__ void __launch_bounds__(512) __attribute__((amdgpu_waves_per_eu(2, 2)))
kA(const float* __restrict__ A,              // [2B][512] fp32 (= combined)
   const unsigned short* __restrict__ fWin,  // frag layout (standard)
   const float* __restrict__ b_in,
   unsigned short* __restrict__ Mf) {        // frag-layout m
    __shared__ __align__(16) char lds[139264];  // 136 KB
    char* buf0 = lds;                           // A tile ping (64 KB fp32)
    char* buf1 = lds + 65536;                   // A tile pong
    char* bnc0 = lds + 131072;                  // bounce ping (4 KB)
    char* bnc1 = lds + 135168;                  // bounce pong

    const int tid = threadIdx.x, w = tid >> 6, l = tid & 63;
    const int lr = l & 15, lg = l >> 4;

    // W_in column-slice (cols w*16..w*16+15) in registers: 16 frags = 64 VGPR
    bf16x8 wfr[16];
    #pragma unroll
    for (int kt = 0; kt < 16; ++kt)
        wfr[kt] = *(const bf16x8*)&fWin[((kt * 8 + w) * 64 + l) * 8];
    const float bb = b_in[w * 16 + lr];

    const char* Ablk = (const char*)(A + (size_t)blockIdx.x * 2048 * 512);

    // loader: per-lane byte offsets within a 64KB tile, r = 0..7.
    // row = w*4 + (r>>1); u_lds = (r&1)*64 + l; src unit = u_lds ^ (row&7).
    int loff[8];
    #pragma unroll
    for (int r = 0; r < 8; ++r) {
        int row = w * 4 + (r >> 1);
        int u = (r & 1) * 64 + l;
        loff[r] = row * 2048 + ((u ^ (row & 7)) * 16);
    }

    // read-side swizzled sub-offsets (lane-constant):
    const int e1 = (((lg * 2)     ^ (lr & 7)) * 16);
    const int e2 = (((lg * 2 + 1) ^ (lr & 7)) * 16);
    const int rb0 = lr * 2048, rb1 = (16 + lr) * 2048;

    #define ISSUE(t, buf) { \
        const char* gb = Ablk + (size_t)(t) * 65536; \
        char* db = (buf) + w * 8192; \
        _Pragma("unroll") \
        for (int r = 0; r < 8; ++r) \
            GLOAD_LDS(gb + loff[r], db + r * 1024); }

    // prologue: tile 0 staged
    ISSUE(0, buf0); VMW0(); BAR();

    for (int t = 0; t < 64; ++t) {
        char* cur = (t & 1) ? buf1 : buf0;
        char* nxt = (t & 1) ? buf0 : buf1;
        char* bc  = (t & 1) ? bnc1 : bnc0;
        if (t < 63) ISSUE(t + 1, nxt);   // DMA loads in flight across compute

        // ---- compute: rows {lr, 16+lr}, cols w*16..+16, K=512 ----
        f32x4 acc0 = (f32x4){0.f, 0.f, 0.f, 0.f};
        f32x4 acc1 = (f32x4){0.f, 0.f, 0.f, 0.f};
        #pragma unroll
        for (int kg = 0; kg < 16; ++kg) {
            f32x4 p0a = *(const f32x4*)(cur + rb0 + kg * 128 + e1);
            f32x4 p0b = *(const f32x4*)(cur + rb0 + kg * 128 + e2);
            f32x4 p1a = *(const f32x4*)(cur + rb1 + kg * 128 + e1);
            f32x4 p1b = *(const f32x4*)(cur + rb1 + kg * 128 + e2);
            acc0 = mfma16(cvt8(p0a, p0b), wfr[kg], acc0);
            acc1 = mfma16(cvt8(p1a, p1b), wfr[kg], acc1);
        }

        // ---- epilogue: bias+relu+pair-mean -> swizzled bounce [16 s][256B] --
        // C layout: H-row (within rowtile) = lg*4+reg, H-col = w*16+lr.
        {
            const int c2 = (w * 16 + lr) * 2;
            float m0 = 0.5f * (fmaxf(acc0[0] + bb, 0.f) + fmaxf(acc0[1] + bb, 0.f));
            float m1 = 0.5f * (fmaxf(acc0[2] + bb, 0.f) + fmaxf(acc0[3] + bb, 0.f));
            int s0 = 2 * lg, s1 = s0 + 1;
            *(unsigned short*)(bc + s0 * 256 + (c2 ^ ((s0 & 7) << 4))) = f2bf(m0);
            *(unsigned short*)(bc + s1 * 256 + (c2 ^ ((s1 & 7) << 4))) = f2bf(m1);
            float m2 = 0.5f * (fmaxf(acc1[0] + bb, 0.f) + fmaxf(acc1[1] + bb, 0.f));
            float m3 = 0.5f * (fmaxf(acc1[2] + bb, 0.f) + fmaxf(acc1[3] + bb, 0.f));
            int s2 = 8 + 2 * lg, s3 = s2 + 1;
            *(unsigned short*)(bc + s2 * 256 + (c2 ^ ((s2 & 7) << 4))) = f2bf(m2);
            *(unsigned short*)(bc + s3 * 256 + (c2 ^ ((s3 & 7) << 4))) = f2bf(m3);
        }

        LGKM0();                    // A-reads + bounce writes complete
        if (t < 63) VMW0();         // own gload_lds for t+1 landed
        BAR();                      // tile t+1 ready; bounce visible block-wide

        // ---- Mf store (waves 0..3, ks = w): 1KB contiguous per wave ----
        if (w < 4) {
            int roff = lr * 256 + ((w * 64 + lg * 16) ^ ((lr & 7) << 4));
            bf16x8 v = *(const bf16x8*)(bc + roff);
            size_t F = (size_t)blockIdx.x * 64 + (size_t)t;
            *(bf16x8*)&Mf[F * 2048 + (size_t)w * 512 + (size_t)l * 8] = v;
        }
        // bc re-written only at epilogue(t+2), which is after BAR(t+1) —
        // and this wave's ds_read completes before its LGKM0(t+1) < BAR(t+1).
    }
    #undef ISSUE
}

// ---------------- kernel B: m -> g1 -> g2 -> sigmoid(score) -----------------
// (R9/R10 verbatim, passed) 512 blocks, A-frags load 1KB-contiguous from Mf.
__global__ void __launch_bounds__(256, 2)
kB(const unsigned short* __restrict__ Mf,
   const unsigned short* __restrict__ fW1,
   const unsigned short* __restrict__ fW2,
   const float* __restrict__ weff,
   const float* __restrict__ b1,
   const float* __restrict__ b2,
   const float* __restrict__ b_out,
   float* __restrict__ out) {
    __shared__ unsigned short lw1[16384];       // 32 KB
    __shared__ unsigned short lw2[8192];        // 16 KB
    __shared__ unsigned short bounce[4][2048];  // 4 waves x 4 KB
    {
        int tid = threadIdx.x;
        const f32x4* s1 = (const f32x4*)fW1;
        f32x4* d1 = (f32x4*)lw1;
        #pragma unroll
        for (int i = 0; i < 8; ++i) d1[i * 256 + tid] = s1[i * 256 + tid];
        const f32x4* s2 = (const f32x4*)fW2;
        f32x4* d2 = (f32x4*)lw2;
        #pragma unroll
        for (int i = 0; i < 4; ++i) d2[i * 256 + tid] = s2[i * 256 + tid];
    }
    __syncthreads();
    const int w = threadIdx.x >> 6, l = threadIdx.x & 63;
    const int lr = l & 15, lg = l >> 4;
    float b1v[8], b2v[4], wev[4];
    #pragma unroll
    for (int n = 0; n < 8; ++n) b1v[n] = b1[n * 16 + lr];
    #pragma unroll
    for (int n = 0; n < 4; ++n) { b2v[n] = b2[n * 16 + lr]; wev[n] = weff[n * 16 + lr]; }
    const float bo = b_out[0];

    for (int t = blockIdx.x; t < NSAMP / 64; t += 512) {
        const int s0 = t * 64 + w * 16;
        const size_t F = (size_t)t * 4 + (size_t)w;
        f32x4 acc1[8];
        #pragma unroll
        for (int n = 0; n < 8; ++n) acc1[n] = (f32x4){0.f, 0.f, 0.f, 0.f};
        #pragma unroll
        for (int ks = 0; ks < 4; ++ks) {
            bf16x8 af = *(const bf16x8*)&Mf[F * 2048 + ks * 512 + l * 8];
            #pragma unroll
            for (int n = 0; n < 8; ++n) {
                bf16x8 bf = *(const bf16x8*)&lw1[((ks * 8 + n) * 64 + l) * 8];
                acc1[n] = __builtin_amdgcn_mfma_f32_16x16x32_bf16(af, bf, acc1[n], 0, 0, 0);
            }
        }
        #pragma unroll
        for (int n = 0; n < 8; ++n) {
            #pragma unroll
            for (int rr = 0; rr < 4; ++rr) {
                float g = fmaxf(acc1[n][rr] + b1v[n], 0.f);
                int row = lg * 4 + rr, col = n * 16 + lr;
                int boff = row * 256 + ((col * 2) ^ ((row & 7) << 4));
                bounce[w][boff >> 1] = f2bf(g);
            }
        }
        f32x4 acc2[4];
        #pragma unroll
        for (int n = 0; n < 4; ++n) acc2[n] = (f32x4){0.f, 0.f, 0.f, 0.f};
        #pragma unroll
        for (int ks = 0; ks < 4; ++ks) {
            int roff = lr * 256 + ((ks * 64 + lg * 16) ^ ((lr & 7) << 4));
            bf16x8 af2 = *(const bf16x8*)((const char*)&bounce[w][0] + roff);
            #pragma unroll
            for (int n = 0; n < 4; ++n) {
                bf16x8 bf = *(const bf16x8*)&lw2[((ks * 4 + n) * 64 + l) * 8];
                acc2[n] = __builtin_amdgcn_mfma_f32_16x16x32_bf16(af2, bf, acc2[n], 0, 0, 0);
            }
        }
        float p0 = 0.f, p1 = 0.f, p2 = 0.f, p3 = 0.f;
        #pragma unroll
        for (int n = 0; n < 4; ++n) {
            p0 += fmaxf(acc2[n][0] + b2v[n], 0.f) * wev[n];
            p1 += fmaxf(acc2[n][1] + b2v[n], 0.f) * wev[n];
            p2 += fmaxf(acc2[n][2] + b2v[n], 0.f) * wev[n];
            p3 += fmaxf(acc2[n][3] + b2v[n], 0.f) * wev[n];
        }
        #pragma unroll
        for (int m = 1; m < 16; m <<= 1) {
            p0 += __shfl_xor(p0, m);
            p1 += __shfl_xor(p1, m);
            p2 += __shfl_xor(p2, m);
            p3 += __shfl_xor(p3, m);
        }
        float s0f = 1.f / (1.f + expf(-(p0 + bo)));
        float s1f = 1.f / (1.f + expf(-(p1 + bo)));
        float s2f = 1.f / (1.f + expf(-(p2 + bo)));
        float s3f = 1.f / (1.f + expf(-(p3 + bo)));
        if (lr < 4) {
            float v = (lr == 0) ? s0f : (lr == 1) ? s1f : (lr == 2) ? s2f : s3f;
            out[s0 + lg * 4 + lr] = v;
        }
    }
}

// ---------------- host launcher ----------------
extern "C" void kernel_launch(void* const* d_in, const int* in_sizes, int n_in,
                              void* d_out, int out_size, void* d_ws, size_t ws_size,
                              hipStream_t stream) {
    const float* combined = (const float*)d_in[0];
    const float* W_in  = (const float*)d_in[1];
    const float* b_in  = (const float*)d_in[2];
    const float* W1    = (const float*)d_in[3];
    const float* b1    = (const float*)d_in[4];
    const float* W2    = (const float*)d_in[5];
    const float* b2    = (const float*)d_in[6];
    const float* W_out = (const float*)d_in[7];
    const float* b_out = (const float*)d_in[8];
    float* out = (float*)d_out;

    char* ws = (char*)d_ws;
    unsigned short* Mf   = (unsigned short*)(ws + WS_M);
    unsigned short* fWin = (unsigned short*)(ws + WS_WIN);
    unsigned short* fW1  = (unsigned short*)(ws + WS_W1);
    unsigned short* fW2  = (unsigned short*)(ws + WS_W2);
    float* weff          = (float*)(ws + WS_WEFF);

    prep_kernel<<<(65536 + 16384 + 8192 + 64 + 255) / 256, 256, 0, stream>>>(
        W_in, W1, W2, W_out, fWin, fW1, fW2, weff);
    kA<<<256, 512, 0, stream>>>(combined, fWin, b_in, Mf);
    kB<<<512, 256, 0, stream>>>(Mf, fW1, fW2, weff, b1, b2, b_out, out);
}